// Round 3
// baseline (1179.686 us; speedup 1.0000x reference)
//
#include <hip/hip_runtime.h>
#include <hip/hip_bf16.h>
#include <cstdint>
#include <cstddef>

typedef __hip_bfloat16 bf16;
typedef __bf16 bf16x8 __attribute__((ext_vector_type(8)));
typedef float f32x4 __attribute__((ext_vector_type(4)));

#define BB 2
#define TT 1024
#define CC 1024
#define HH 16

__device__ __forceinline__ bf16 f2b(float v){ return __float2bfloat16(v); }

// ---------------- transpose+convert: f32 [R][S] -> bf16 [S][R] ----------------
__global__ __launch_bounds__(256) void transpose_kernel(const float* __restrict__ in,
                                                        bf16* __restrict__ out, int R, int S)
{
    __shared__ float tile[32][33];
    int s0 = blockIdx.x * 32, r0 = blockIdx.y * 32;
    int tx = threadIdx.x & 31, ty = threadIdx.x >> 5;
#pragma unroll
    for (int i = 0; i < 4; i++) {
        int r = r0 + ty + i * 8, s = s0 + tx;
        if (r < R && s < S) tile[ty + i * 8][tx] = in[(size_t)r * S + s];
    }
    __syncthreads();
#pragma unroll
    for (int i = 0; i < 4; i++) {
        int s = s0 + ty + i * 8, r = r0 + tx;
        if (s < S && r < R) out[(size_t)s * R + r] = f2b(tile[tx][ty + i * 8]);
    }
}

// ---------------- token-shift mix (f32 in -> bf16 out) + v_first passthrough ----------------
__global__ __launch_bounds__(256) void mix_kernel(
    const float* __restrict__ x, const float* __restrict__ vfirst,
    const float* __restrict__ mr, const float* __restrict__ mw, const float* __restrict__ mk,
    const float* __restrict__ mv, const float* __restrict__ ma, const float* __restrict__ mg,
    bf16* __restrict__ xr, bf16* __restrict__ xw, bf16* __restrict__ xk,
    bf16* __restrict__ xv, bf16* __restrict__ xa, bf16* __restrict__ xg,
    float* __restrict__ vout)
{
    int row = blockIdx.x;
    int t = row & (TT - 1);
    size_t base = (size_t)row * CC;
    for (int c = threadIdx.x; c < CC; c += 256) {
        float xc = x[base + c];
        float xp = (t > 0) ? x[base - CC + c] : 0.f;
        float d = xp - xc;
        xr[base + c] = f2b(xc + d * mr[c]);
        xw[base + c] = f2b(xc + d * mw[c]);
        xk[base + c] = f2b(xc + d * mk[c]);
        xv[base + c] = f2b(xc + d * mv[c]);
        xa[base + c] = f2b(xc + d * ma[c]);
        xg[base + c] = f2b(xc + d * mg[c]);
        vout[base + c] = vfirst[base + c];   // exact f32 passthrough
    }
}

// ---------------- MFMA GEMM: out = epilogue(A[M,K] @ BT[N,K]^T), bf16 operands ----------------
// MODE: 0 f32 plain | 1 bf16 plain | 2 bf16 tanh | 3 bf16 sigmoid
//       4 f32 decay(bias) | 5 f32 sigmoid(+bias) | 6 f32 v-mix(bias, aux0=vraw, aux1=vfirst f32)
template<int MODE>
__global__ __launch_bounds__(256) void gemm_kernel(
    const bf16* __restrict__ A, const bf16* __restrict__ BT,
    int M, int N, int K,
    float* __restrict__ outF, bf16* __restrict__ outB,
    const float* __restrict__ bias, const float* __restrict__ aux0,
    const float* __restrict__ aux1)
{
    __shared__ __align__(16) bf16 Atile[128 * 32];
    __shared__ __align__(16) bf16 Btile[128 * 32];
    int tid = threadIdx.x;
    int w = tid >> 6, lane = tid & 63;
    int wr = w >> 1, wc = w & 1;
    int quad = lane >> 4, l16 = lane & 15;
    int m0 = blockIdx.x * 128, n0 = blockIdx.y * 128;

    f32x4 zero = {0.f, 0.f, 0.f, 0.f};
    f32x4 acc[4][4];
#pragma unroll
    for (int i = 0; i < 4; i++)
#pragma unroll
        for (int j = 0; j < 4; j++) acc[i][j] = zero;

    int rr = lane >> 2;            // 0..15
    int cs = lane & 3;             // chunk slot in LDS
    int ra0 = w * 32 + rr;         // rows this lane stages
    int ra1 = ra0 + 16;
    int cg0 = cs ^ ((ra0 >> 1) & 3);   // global chunk (XOR swizzle)
    int cg1 = cs ^ ((ra1 >> 1) & 3);

    for (int k0 = 0; k0 < K; k0 += 32) {
        uint4 av0 = *reinterpret_cast<const uint4*>(A  + (size_t)(m0 + ra0) * K + k0 + cg0 * 8);
        uint4 av1 = *reinterpret_cast<const uint4*>(A  + (size_t)(m0 + ra1) * K + k0 + cg1 * 8);
        uint4 bv0 = *reinterpret_cast<const uint4*>(BT + (size_t)(n0 + ra0) * K + k0 + cg0 * 8);
        uint4 bv1 = *reinterpret_cast<const uint4*>(BT + (size_t)(n0 + ra1) * K + k0 + cg1 * 8);
        __syncthreads();           // previous tile's reads complete
        *reinterpret_cast<uint4*>(&Atile[ra0 * 32 + cs * 8]) = av0;
        *reinterpret_cast<uint4*>(&Atile[ra1 * 32 + cs * 8]) = av1;
        *reinterpret_cast<uint4*>(&Btile[ra0 * 32 + cs * 8]) = bv0;
        *reinterpret_cast<uint4*>(&Btile[ra1 * 32 + cs * 8]) = bv1;
        __syncthreads();           // staging visible

        bf16x8 af[4], bfr[4];
#pragma unroll
        for (int mi = 0; mi < 4; mi++) {
            int m = wr * 64 + mi * 16 + l16;
            int c2 = quad ^ ((m >> 1) & 3);
            af[mi] = *reinterpret_cast<const bf16x8*>(&Atile[m * 32 + c2 * 8]);
        }
#pragma unroll
        for (int ni = 0; ni < 4; ni++) {
            int n = wc * 64 + ni * 16 + l16;
            int c2 = quad ^ ((n >> 1) & 3);
            bfr[ni] = *reinterpret_cast<const bf16x8*>(&Btile[n * 32 + c2 * 8]);
        }
#pragma unroll
        for (int mi = 0; mi < 4; mi++)
#pragma unroll
            for (int ni = 0; ni < 4; ni++)
                acc[mi][ni] = __builtin_amdgcn_mfma_f32_16x16x32_bf16(af[mi], bfr[ni], acc[mi][ni], 0, 0, 0);
    }

#pragma unroll
    for (int mi = 0; mi < 4; mi++)
#pragma unroll
        for (int ni = 0; ni < 4; ni++)
#pragma unroll
            for (int rg = 0; rg < 4; rg++) {
                int m = m0 + wr * 64 + mi * 16 + quad * 4 + rg;
                int n = n0 + wc * 64 + ni * 16 + l16;
                if (n < N) {
                    size_t idx = (size_t)m * N + n;
                    float v = acc[mi][ni][rg];
                    if (MODE == 0) outF[idx] = v;
                    else if (MODE == 1) outB[idx] = f2b(v);
                    else if (MODE == 2) outB[idx] = f2b(tanhf(v));
                    else if (MODE == 3) outB[idx] = f2b(1.f / (1.f + expf(-v)));
                    else if (MODE == 4) {
                        float xx = v + bias[n];
                        float ww = -log1pf(expf(-xx)) - 0.5f;   // -softplus(-x) - 0.5
                        outF[idx] = expf(-expf(ww));            // decay in (0,1)
                    } else if (MODE == 5) {
                        float xx = v + bias[n];
                        outF[idx] = 1.f / (1.f + expf(-xx));
                    } else if (MODE == 6) {
                        float gate = 1.f / (1.f + expf(-(v + bias[n])));
                        float vr = aux0[idx];
                        float vf = aux1[idx];
                        outF[idx] = vr + (vf - vr) * gate;
                    }
                }
            }
}

// ---------------- kk normalize + k scale (per head) ----------------
__global__ __launch_bounds__(256) void kk_kernel(
    float* __restrict__ k, const float* __restrict__ a,
    const float* __restrict__ kkw, const float* __restrict__ kaw,
    float* __restrict__ kkbuf)
{
    int tid = threadIdx.x;
    int wave = tid >> 6, lane = tid & 63;
    int idx = blockIdx.x * 4 + wave;        // (b*T+t)*16 + h
    size_t off = (size_t)idx * 64 + lane;
    int c = (idx & 15) * 64 + lane;
    float kraw = k[off];
    float kkv = kraw * kkw[c];
    float s = kkv * kkv;
#pragma unroll
    for (int m = 32; m; m >>= 1) s += __shfl_xor(s, m);
    kkbuf[off] = kkv / fmaxf(sqrtf(s), 1e-12f);
    float av = a[off];
    k[off] = kraw * (1.f + (av - 1.f) * kaw[c]);
}

// ---------------- sequential state recurrence ----------------
// thread (i = tid>>2, q = tid&3) owns S[i][16q .. 16q+16)
__global__ __launch_bounds__(256) void scan_kernel(
    const float* __restrict__ rbuf, const float* __restrict__ dbuf,
    const float* __restrict__ kbuf, const float* __restrict__ vbuf,
    const float* __restrict__ kkbuf, const float* __restrict__ abuf,
    float* __restrict__ ybuf)
{
    __shared__ float lds[384];
    int tid = threadIdx.x;
    int b = blockIdx.x >> 4, h = blockIdx.x & 15;
    int i = tid >> 2, q = tid & 3, jb = q * 16;
    float S[16];
#pragma unroll
    for (int m = 0; m < 16; m++) S[m] = 0.f;

    const float* bufs[6] = {rbuf, dbuf, kbuf, vbuf, kkbuf, abuf};
    size_t base = (size_t)b * TT * CC + h * 64;
    int f1 = tid;
    const float* p1 = bufs[f1 >> 6] + base + (f1 & 63);
    int f2 = 256 + tid;
    int vec2 = (tid < 128) ? (f2 >> 6) : 0;
    const float* p2 = bufs[vec2] + base + (f2 & 63);

    float v1 = *p1; p1 += CC;
    float v2 = (tid < 128) ? *p2 : 0.f; p2 += CC;

    float* yout = ybuf + base + i;

    for (int t = 0; t < TT; t++) {
        lds[f1] = v1;
        if (tid < 128) lds[f2] = v2;
        __syncthreads();
        if (t + 1 < TT) {                 // prefetch next step (overlaps compute)
            v1 = *p1; p1 += CC;
            if (tid < 128) { v2 = *p2; p2 += CC; }
        }
        const float* rv  = lds;
        const float* dv  = lds + 64;
        const float* kv  = lds + 128;
        const float* vv  = lds + 192;
        const float* kkv = lds + 256;
        const float* av  = lds + 320;

        float sa = 0.f;                   // sa_i = sum_j S[i][j] * (-kk_j)
#pragma unroll
        for (int m = 0; m < 16; m++) sa -= S[m] * kkv[jb + m];
        sa += __shfl_xor(sa, 1); sa += __shfl_xor(sa, 2);

        float vi = vv[i];
        float o = 0.f;
#pragma unroll
        for (int m = 0; m < 16; m++) {
            int j = jb + m;
            float bbj = kkv[j] * av[j];   // b_j = kk_j * a_j
            S[m] = S[m] * dv[j] + sa * bbj + vi * kv[j];
            o += S[m] * rv[j];
        }
        o += __shfl_xor(o, 1); o += __shfl_xor(o, 2);
        if (q == 0) *yout = o;
        yout += CC;
        __syncthreads();
    }
}

// ---------------- groupnorm + residual + gate -> z (bf16) ----------------
__global__ __launch_bounds__(64) void gn_kernel(
    const float* __restrict__ y, const float* __restrict__ r, const float* __restrict__ k,
    const float* __restrict__ v, const float* __restrict__ g,
    const float* __restrict__ lnw, const float* __restrict__ lnb,
    const float* __restrict__ rk, bf16* __restrict__ z)
{
    int idx = blockIdx.x;                 // (b*T+t)*16 + h
    int lane = threadIdx.x;
    size_t off = (size_t)idx * 64 + lane;
    int c = (idx & 15) * 64 + lane;
    float yv = y[off];
    float rv = r[off], kv = k[off], vv = v[off];
    float s1 = yv, s2 = yv * yv, s3 = rv * kv * rk[c];
#pragma unroll
    for (int m = 32; m; m >>= 1) {
        s1 += __shfl_xor(s1, m);
        s2 += __shfl_xor(s2, m);
        s3 += __shfl_xor(s3, m);
    }
    float mu = s1 * (1.f / 64.f);
    float var = fmaxf(s2 * (1.f / 64.f) - mu * mu, 0.f);   // guard vs cancellation
    float yn = (yv - mu) * rsqrtf(var + 64e-5f) * lnw[c] + lnb[c];
    float out = (yn + s3 * vv) * g[off];
    z[off] = f2b(out);
}

// ---------------- host ----------------
extern "C" void kernel_launch(void* const* d_in, const int* in_sizes, int n_in,
                              void* d_out, int out_size, void* d_ws, size_t ws_size,
                              hipStream_t stream)
{
    const float* x       = (const float*)d_in[0];
    const float* v_first = (const float*)d_in[1];
    const float* x_r = (const float*)d_in[2];
    const float* x_w = (const float*)d_in[3];
    const float* x_k = (const float*)d_in[4];
    const float* x_v = (const float*)d_in[5];
    const float* x_a = (const float*)d_in[6];
    const float* x_g = (const float*)d_in[7];
    const float* w1 = (const float*)d_in[8];
    const float* w2 = (const float*)d_in[9];
    const float* w0 = (const float*)d_in[10];
    const float* a1 = (const float*)d_in[11];
    const float* a2 = (const float*)d_in[12];
    const float* a0 = (const float*)d_in[13];
    const float* v1 = (const float*)d_in[14];
    const float* v2 = (const float*)d_in[15];
    const float* v0 = (const float*)d_in[16];
    const float* g1 = (const float*)d_in[17];
    const float* g2 = (const float*)d_in[18];
    const float* k_k = (const float*)d_in[19];
    const float* k_a = (const float*)d_in[20];
    const float* r_k = (const float*)d_in[21];
    const float* W_r = (const float*)d_in[22];
    const float* W_k = (const float*)d_in[23];
    const float* W_v = (const float*)d_in[24];
    const float* W_o = (const float*)d_in[25];
    const float* ln_w = (const float*)d_in[26];
    const float* ln_b = (const float*)d_in[27];

    const size_t BTC = (size_t)BB * TT * CC;   // 2M
    const int M = BB * TT;                     // 2048

    char* ws = (char*)d_ws;
    size_t off = 0;
    auto alloc = [&](size_t bytes) -> char* {
        char* p = ws + off;
        off += (bytes + 255) & ~(size_t)255;
        return p;
    };

    bf16* xr = (bf16*)alloc(BTC * 2);
    bf16* xw = (bf16*)alloc(BTC * 2);
    bf16* xk = (bf16*)alloc(BTC * 2);
    bf16* xv = (bf16*)alloc(BTC * 2);
    bf16* xa = (bf16*)alloc(BTC * 2);
    bf16* xg = (bf16*)alloc(BTC * 2);

    bf16* WrT = (bf16*)alloc(1024 * 1024 * 2);
    bf16* WkT = (bf16*)alloc(1024 * 1024 * 2);
    bf16* WvT = (bf16*)alloc(1024 * 1024 * 2);
    bf16* WoT = (bf16*)alloc(1024 * 1024 * 2);
    bf16* w1T = (bf16*)alloc(128 * 1024 * 2);   // 64 rows used, rest benign poison
    bf16* w2T = (bf16*)alloc(1024 * 64 * 2);
    bf16* a1T = (bf16*)alloc(128 * 1024 * 2);
    bf16* a2T = (bf16*)alloc(1024 * 64 * 2);
    bf16* v1T = (bf16*)alloc(128 * 1024 * 2);   // 32 rows used
    bf16* v2T = (bf16*)alloc(1024 * 32 * 2);
    bf16* g1T = (bf16*)alloc(128 * 1024 * 2);
    bf16* g2T = (bf16*)alloc(1024 * 128 * 2);

    bf16* h_w = (bf16*)alloc((size_t)M * 64 * 2);
    bf16* h_a = (bf16*)alloc((size_t)M * 64 * 2);
    bf16* h_v = (bf16*)alloc((size_t)M * 32 * 2);
    bf16* h_g = (bf16*)alloc((size_t)M * 128 * 2);

    float* rbuf  = (float*)alloc(BTC * 4);
    float* kbuf  = (float*)alloc(BTC * 4);
    float* vraw  = (float*)alloc(BTC * 4);   // reused as ybuf after stage-2 v
    float* vbuf  = (float*)alloc(BTC * 4);
    float* dbuf  = (float*)alloc(BTC * 4);   // reused as zbuf (bf16) after scan
    float* abuf  = (float*)alloc(BTC * 4);
    float* kkbuf = (float*)alloc(BTC * 4);   // reused as gbuf after scan

    float* ybuf = vraw;        // alias: vraw dead after stage-2 v GEMM
    bf16*  zbuf = (bf16*)dbuf; // alias: dbuf dead after scan
    float* gbuf = kkbuf;       // alias: kkbuf dead after scan

    (void)in_sizes; (void)n_in; (void)out_size; (void)ws_size;

    // weight transposes+convert [k][n] f32 -> [n][k] bf16
    auto tr = [&](const float* in, bf16* out, int R, int S) {
        dim3 g((S + 31) / 32, (R + 31) / 32);
        transpose_kernel<<<g, 256, 0, stream>>>(in, out, R, S);
    };
    tr(W_r, WrT, 1024, 1024); tr(W_k, WkT, 1024, 1024);
    tr(W_v, WvT, 1024, 1024); tr(W_o, WoT, 1024, 1024);
    tr(w1, w1T, 1024, 64);  tr(w2, w2T, 64, 1024);
    tr(a1, a1T, 1024, 64);  tr(a2, a2T, 64, 1024);
    tr(v1, v1T, 1024, 32);  tr(v2, v2T, 32, 1024);
    tr(g1, g1T, 1024, 128); tr(g2, g2T, 128, 1024);

    // token-shift mix (+ v_first passthrough to second output, f32)
    float* vout = (float*)d_out + BTC;
    mix_kernel<<<BB * TT, 256, 0, stream>>>(x, v_first, x_r, x_w, x_k, x_v, x_a, x_g,
                                            xr, xw, xk, xv, xa, xg, vout);

    auto gg = [&](int Mm, int Nn) { return dim3(Mm / 128, (Nn + 127) / 128); };
    const float* nF = nullptr;

    // big projections
    gemm_kernel<0><<<gg(M, 1024), 256, 0, stream>>>(xr, WrT, M, 1024, 1024, rbuf, nullptr, nF, nF, nF);
    gemm_kernel<0><<<gg(M, 1024), 256, 0, stream>>>(xk, WkT, M, 1024, 1024, kbuf, nullptr, nF, nF, nF);
    gemm_kernel<0><<<gg(M, 1024), 256, 0, stream>>>(xv, WvT, M, 1024, 1024, vraw, nullptr, nF, nF, nF);

    // lora stage 1
    gemm_kernel<2><<<gg(M, 64), 256, 0, stream>>>(xw, w1T, M, 64, 1024, nullptr, h_w, nF, nF, nF);
    gemm_kernel<1><<<gg(M, 64), 256, 0, stream>>>(xa, a1T, M, 64, 1024, nullptr, h_a, nF, nF, nF);
    gemm_kernel<1><<<gg(M, 32), 256, 0, stream>>>(xv, v1T, M, 32, 1024, nullptr, h_v, nF, nF, nF);
    gemm_kernel<3><<<gg(M, 128), 256, 0, stream>>>(xg, g1T, M, 128, 1024, nullptr, h_g, nF, nF, nF);

    // lora stage 2 (fused epilogues)
    gemm_kernel<4><<<gg(M, 1024), 256, 0, stream>>>(h_w, w2T, M, 1024, 64, dbuf, nullptr, w0, nF, nF);
    gemm_kernel<5><<<gg(M, 1024), 256, 0, stream>>>(h_a, a2T, M, 1024, 64, abuf, nullptr, a0, nF, nF);
    gemm_kernel<6><<<gg(M, 1024), 256, 0, stream>>>(h_v, v2T, M, 1024, 32, vbuf, nullptr, v0, vraw, v_first);

    // kk normalize + k scale
    kk_kernel<<<BB * TT * HH / 4, 256, 0, stream>>>(kbuf, abuf, k_k, k_a, kkbuf);

    // sequential recurrence (writes ybuf = vraw region)
    scan_kernel<<<BB * HH, 256, 0, stream>>>(rbuf, dbuf, kbuf, vbuf, kkbuf, abuf, ybuf);

    // lora stage 2 g (after scan: gbuf aliases kkbuf)
    gemm_kernel<0><<<gg(M, 1024), 256, 0, stream>>>(h_g, g2T, M, 1024, 128, gbuf, nullptr, nF, nF, nF);

    // groupnorm + residual + gate (writes zbuf = dbuf region)
    gn_kernel<<<BB * TT * HH, 64, 0, stream>>>(ybuf, rbuf, kbuf, vbuf, gbuf, ln_w, ln_b, r_k, zbuf);

    // output projection -> d_out (f32)
    gemm_kernel<0><<<gg(M, 1024), 256, 0, stream>>>(zbuf, WoT, M, 1024, 1024, (float*)d_out, nullptr, nF, nF, nF);
}

// Round 4
// 1085.780 us; speedup vs baseline: 1.0865x; 1.0865x over previous
//
#include <hip/hip_runtime.h>
#include <hip/hip_bf16.h>
#include <cstdint>
#include <cstddef>

typedef __hip_bfloat16 bf16;
typedef __bf16 bf16x8 __attribute__((ext_vector_type(8)));
typedef float f32x4 __attribute__((ext_vector_type(4)));

#define BB 2
#define TT 1024
#define CC 1024
#define HH 16

__device__ __forceinline__ bf16 f2b(float v){ return __float2bfloat16(v); }

// ---------------- transpose+convert: f32 [R][S] -> bf16 [S][R] ----------------
__global__ __launch_bounds__(256) void transpose_kernel(const float* __restrict__ in,
                                                        bf16* __restrict__ out, int R, int S)
{
    __shared__ float tile[32][33];
    int s0 = blockIdx.x * 32, r0 = blockIdx.y * 32;
    int tx = threadIdx.x & 31, ty = threadIdx.x >> 5;
#pragma unroll
    for (int i = 0; i < 4; i++) {
        int r = r0 + ty + i * 8, s = s0 + tx;
        if (r < R && s < S) tile[ty + i * 8][tx] = in[(size_t)r * S + s];
    }
    __syncthreads();
#pragma unroll
    for (int i = 0; i < 4; i++) {
        int s = s0 + ty + i * 8, r = r0 + tx;
        if (s < S && r < R) out[(size_t)s * R + r] = f2b(tile[tx][ty + i * 8]);
    }
}

// ---------------- token-shift mix (f32 in -> bf16 out) + v_first passthrough ----------------
__global__ __launch_bounds__(256) void mix_kernel(
    const float* __restrict__ x, const float* __restrict__ vfirst,
    const float* __restrict__ mr, const float* __restrict__ mw, const float* __restrict__ mk,
    const float* __restrict__ mv, const float* __restrict__ ma, const float* __restrict__ mg,
    bf16* __restrict__ xr, bf16* __restrict__ xw, bf16* __restrict__ xk,
    bf16* __restrict__ xv, bf16* __restrict__ xa, bf16* __restrict__ xg,
    float* __restrict__ vout)
{
    int row = blockIdx.x;
    int t = row & (TT - 1);
    size_t base = (size_t)row * CC;
    for (int c = threadIdx.x; c < CC; c += 256) {
        float xc = x[base + c];
        float xp = (t > 0) ? x[base - CC + c] : 0.f;
        float d = xp - xc;
        xr[base + c] = f2b(xc + d * mr[c]);
        xw[base + c] = f2b(xc + d * mw[c]);
        xk[base + c] = f2b(xc + d * mk[c]);
        xv[base + c] = f2b(xc + d * mv[c]);
        xa[base + c] = f2b(xc + d * ma[c]);
        xg[base + c] = f2b(xc + d * mg[c]);
        vout[base + c] = vfirst[base + c];   // exact f32 passthrough
    }
}

// ---------------- MFMA GEMM: out = epilogue(A[M,K] @ BT[N,K]^T), bf16 operands ----------------
// MODE: 0 f32 plain | 1 bf16 plain | 2 bf16 tanh | 3 bf16 sigmoid
//       4 f32 decay(bias) | 5 f32 sigmoid(+bias) | 6 f32 v-mix(bias, aux0=vraw, aux1=vfirst f32)
template<int MODE>
__global__ __launch_bounds__(256) void gemm_kernel(
    const bf16* __restrict__ A, const bf16* __restrict__ BT,
    int M, int N, int K,
    float* __restrict__ outF, bf16* __restrict__ outB,
    const float* __restrict__ bias, const float* __restrict__ aux0,
    const float* __restrict__ aux1)
{
    __shared__ __align__(16) bf16 Atile[128 * 32];
    __shared__ __align__(16) bf16 Btile[128 * 32];
    int tid = threadIdx.x;
    int w = tid >> 6, lane = tid & 63;
    int wr = w >> 1, wc = w & 1;
    int quad = lane >> 4, l16 = lane & 15;
    int m0 = blockIdx.x * 128, n0 = blockIdx.y * 128;

    f32x4 zero = {0.f, 0.f, 0.f, 0.f};
    f32x4 acc[4][4];
#pragma unroll
    for (int i = 0; i < 4; i++)
#pragma unroll
        for (int j = 0; j < 4; j++) acc[i][j] = zero;

    int rr = lane >> 2;            // 0..15
    int cs = lane & 3;             // chunk slot in LDS
    int ra0 = w * 32 + rr;         // rows this lane stages
    int ra1 = ra0 + 16;
    int cg0 = cs ^ ((ra0 >> 1) & 3);   // global chunk (XOR swizzle)
    int cg1 = cs ^ ((ra1 >> 1) & 3);

    for (int k0 = 0; k0 < K; k0 += 32) {
        uint4 av0 = *reinterpret_cast<const uint4*>(A  + (size_t)(m0 + ra0) * K + k0 + cg0 * 8);
        uint4 av1 = *reinterpret_cast<const uint4*>(A  + (size_t)(m0 + ra1) * K + k0 + cg1 * 8);
        uint4 bv0 = *reinterpret_cast<const uint4*>(BT + (size_t)(n0 + ra0) * K + k0 + cg0 * 8);
        uint4 bv1 = *reinterpret_cast<const uint4*>(BT + (size_t)(n0 + ra1) * K + k0 + cg1 * 8);
        __syncthreads();           // previous tile's reads complete
        *reinterpret_cast<uint4*>(&Atile[ra0 * 32 + cs * 8]) = av0;
        *reinterpret_cast<uint4*>(&Atile[ra1 * 32 + cs * 8]) = av1;
        *reinterpret_cast<uint4*>(&Btile[ra0 * 32 + cs * 8]) = bv0;
        *reinterpret_cast<uint4*>(&Btile[ra1 * 32 + cs * 8]) = bv1;
        __syncthreads();           // staging visible

        bf16x8 af[4], bfr[4];
#pragma unroll
        for (int mi = 0; mi < 4; mi++) {
            int m = wr * 64 + mi * 16 + l16;
            int c2 = quad ^ ((m >> 1) & 3);
            af[mi] = *reinterpret_cast<const bf16x8*>(&Atile[m * 32 + c2 * 8]);
        }
#pragma unroll
        for (int ni = 0; ni < 4; ni++) {
            int n = wc * 64 + ni * 16 + l16;
            int c2 = quad ^ ((n >> 1) & 3);
            bfr[ni] = *reinterpret_cast<const bf16x8*>(&Btile[n * 32 + c2 * 8]);
        }
#pragma unroll
        for (int mi = 0; mi < 4; mi++)
#pragma unroll
            for (int ni = 0; ni < 4; ni++)
                acc[mi][ni] = __builtin_amdgcn_mfma_f32_16x16x32_bf16(af[mi], bfr[ni], acc[mi][ni], 0, 0, 0);
    }

#pragma unroll
    for (int mi = 0; mi < 4; mi++)
#pragma unroll
        for (int ni = 0; ni < 4; ni++)
#pragma unroll
            for (int rg = 0; rg < 4; rg++) {
                int m = m0 + wr * 64 + mi * 16 + quad * 4 + rg;
                int n = n0 + wc * 64 + ni * 16 + l16;
                if (n < N) {
                    size_t idx = (size_t)m * N + n;
                    float v = acc[mi][ni][rg];
                    if (MODE == 0) outF[idx] = v;
                    else if (MODE == 1) outB[idx] = f2b(v);
                    else if (MODE == 2) outB[idx] = f2b(tanhf(v));
                    else if (MODE == 3) outB[idx] = f2b(1.f / (1.f + expf(-v)));
                    else if (MODE == 4) {
                        float xx = v + bias[n];
                        float ww = -log1pf(expf(-xx)) - 0.5f;   // -softplus(-x) - 0.5
                        outF[idx] = expf(-expf(ww));            // decay in (0,1)
                    } else if (MODE == 5) {
                        float xx = v + bias[n];
                        outF[idx] = 1.f / (1.f + expf(-xx));
                    } else if (MODE == 6) {
                        float gate = 1.f / (1.f + expf(-(v + bias[n])));
                        float vr = aux0[idx];
                        float vf = aux1[idx];
                        outF[idx] = vr + (vf - vr) * gate;
                    }
                }
            }
}

// ---------------- kk normalize + k scale (per head) ----------------
__global__ __launch_bounds__(256) void kk_kernel(
    float* __restrict__ k, const float* __restrict__ a,
    const float* __restrict__ kkw, const float* __restrict__ kaw,
    float* __restrict__ kkbuf)
{
    int tid = threadIdx.x;
    int wave = tid >> 6, lane = tid & 63;
    int idx = blockIdx.x * 4 + wave;        // (b*T+t)*16 + h
    size_t off = (size_t)idx * 64 + lane;
    int c = (idx & 15) * 64 + lane;
    float kraw = k[off];
    float kkv = kraw * kkw[c];
    float s = kkv * kkv;
#pragma unroll
    for (int m = 32; m; m >>= 1) s += __shfl_xor(s, m);
    kkbuf[off] = kkv / fmaxf(sqrtf(s), 1e-12f);
    float av = a[off];
    k[off] = kraw * (1.f + (av - 1.f) * kaw[c]);
}

// ---------------- sequential state recurrence (barrier-free, 1 wave/block) ----------------
// Block = 64 lanes = one wave; owns rows [wq*16, wq*16+16) of one (b,h) state.
// Lane (i = lane>>2, q = lane&3) owns S[row][16q .. 16q+16). Private double-buffered
// LDS copy of the 6 per-step vectors; depth-2 register prefetch; zero __syncthreads.
__global__ __launch_bounds__(64) void scan_kernel(
    const float* __restrict__ rbuf, const float* __restrict__ dbuf,
    const float* __restrict__ kbuf, const float* __restrict__ vbuf,
    const float* __restrict__ kkbuf, const float* __restrict__ abuf,
    float* __restrict__ ybuf)
{
    __shared__ __align__(16) float lds[2][384];
    int lane = threadIdx.x;
    int bh = blockIdx.x >> 2;
    int b = bh >> 4, h = bh & 15;
    int wq = blockIdx.x & 3;
    int row = wq * 16 + (lane >> 2);
    int q = lane & 3, jb = q * 16;

    float S[16];
#pragma unroll
    for (int m = 0; m < 16; m++) S[m] = 0.f;

    size_t base = (size_t)b * TT * CC + h * 64 + lane;
    const float* pr = rbuf  + base;
    const float* pd = dbuf  + base;
    const float* pk = kbuf  + base;
    const float* pv = vbuf  + base;
    const float* pq = kkbuf + base;
    const float* pa = abuf  + base;

    float A0[6], A1[6];
    // preload t=0, t=1
    A0[0] = pr[0];  A0[1] = pd[0];  A0[2] = pk[0];
    A0[3] = pv[0];  A0[4] = pq[0];  A0[5] = pa[0];
    A0 == A0;
    A1[0] = pr[CC]; A1[1] = pd[CC]; A1[2] = pk[CC];
    A1[3] = pv[CC]; A1[4] = pq[CC]; A1[5] = pa[CC];

    float* py = ybuf + (size_t)b * TT * CC + h * 64 + row;

    for (int t = 0; t < TT; t += 2) {
#pragma unroll
        for (int half = 0; half < 2; half++) {
            float* L = lds[half];
            float* Areg = half ? A1 : A0;
            // stage this step's vectors into the wave-private LDS buffer
            L[lane]       = Areg[0];
            L[lane + 64]  = Areg[1];
            L[lane + 128] = Areg[2];
            L[lane + 192] = Areg[3];
            L[lane + 256] = Areg[4];
            L[lane + 320] = Areg[5];
            // prefetch t+2 (this half's next use) — clamp at end
            {
                int tn = t + 2 + half;
                size_t o = (size_t)(tn < TT ? tn : TT - 1) * CC;
                Areg[0] = pr[o]; Areg[1] = pd[o]; Areg[2] = pk[o];
                Areg[3] = pv[o]; Areg[4] = pq[o]; Areg[5] = pa[o];
            }
            const float* rv  = L;
            const float* dv  = L + 64;
            const float* kv  = L + 128;
            const float* vv  = L + 192;
            const float* qv  = L + 256;   // kk
            const float* av  = L + 320;

            float sa = 0.f;               // sa_row = sum_j S[row][j] * (-kk_j)
#pragma unroll
            for (int m = 0; m < 16; m++) sa -= S[m] * qv[jb + m];
            sa += __shfl_xor(sa, 1); sa += __shfl_xor(sa, 2);

            float vi = vv[row];
            float o = 0.f;
#pragma unroll
            for (int m = 0; m < 16; m++) {
                int j = jb + m;
                float bbj = qv[j] * av[j];   // b_j = kk_j * a_j
                S[m] = S[m] * dv[j] + sa * bbj + vi * kv[j];
                o += S[m] * rv[j];
            }
            o += __shfl_xor(o, 1); o += __shfl_xor(o, 2);
            if (q == 0) *py = o;
            py += CC;
        }
    }
}

// ---------------- groupnorm + residual + gate -> z (bf16) ----------------
__global__ __launch_bounds__(64) void gn_kernel(
    const float* __restrict__ y, const float* __restrict__ r, const float* __restrict__ k,
    const float* __restrict__ v, const float* __restrict__ g,
    const float* __restrict__ lnw, const float* __restrict__ lnb,
    const float* __restrict__ rk, bf16* __restrict__ z)
{
    int idx = blockIdx.x;                 // (b*T+t)*16 + h
    int lane = threadIdx.x;
    size_t off = (size_t)idx * 64 + lane;
    int c = (idx & 15) * 64 + lane;
    float yv = y[off];
    float rv = r[off], kv = k[off], vv = v[off];
    float s1 = yv, s2 = yv * yv, s3 = rv * kv * rk[c];
#pragma unroll
    for (int m = 32; m; m >>= 1) {
        s1 += __shfl_xor(s1, m);
        s2 += __shfl_xor(s2, m);
        s3 += __shfl_xor(s3, m);
    }
    float mu = s1 * (1.f / 64.f);
    float var = fmaxf(s2 * (1.f / 64.f) - mu * mu, 0.f);   // guard vs cancellation
    float yn = (yv - mu) * rsqrtf(var + 64e-5f) * lnw[c] + lnb[c];
    float out = (yn + s3 * vv) * g[off];
    z[off] = f2b(out);
}

// ---------------- host ----------------
extern "C" void kernel_launch(void* const* d_in, const int* in_sizes, int n_in,
                              void* d_out, int out_size, void* d_ws, size_t ws_size,
                              hipStream_t stream)
{
    const float* x       = (const float*)d_in[0];
    const float* v_first = (const float*)d_in[1];
    const float* x_r = (const float*)d_in[2];
    const float* x_w = (const float*)d_in[3];
    const float* x_k = (const float*)d_in[4];
    const float* x_v = (const float*)d_in[5];
    const float* x_a = (const float*)d_in[6];
    const float* x_g = (const float*)d_in[7];
    const float* w1 = (const float*)d_in[8];
    const float* w2 = (const float*)d_in[9];
    const float* w0 = (const float*)d_in[10];
    const float* a1 = (const float*)d_in[11];
    const float* a2 = (const float*)d_in[12];
    const float* a0 = (const float*)d_in[13];
    const float* v1 = (const float*)d_in[14];
    const float* v2 = (const float*)d_in[15];
    const float* v0 = (const float*)d_in[16];
    const float* g1 = (const float*)d_in[17];
    const float* g2 = (const float*)d_in[18];
    const float* k_k = (const float*)d_in[19];
    const float* k_a = (const float*)d_in[20];
    const float* r_k = (const float*)d_in[21];
    const float* W_r = (const float*)d_in[22];
    const float* W_k = (const float*)d_in[23];
    const float* W_v = (const float*)d_in[24];
    const float* W_o = (const float*)d_in[25];
    const float* ln_w = (const float*)d_in[26];
    const float* ln_b = (const float*)d_in[27];

    const size_t BTC = (size_t)BB * TT * CC;   // 2M
    const int M = BB * TT;                     // 2048

    char* ws = (char*)d_ws;
    size_t off = 0;
    auto alloc = [&](size_t bytes) -> char* {
        char* p = ws + off;
        off += (bytes + 255) & ~(size_t)255;
        return p;
    };

    bf16* xr = (bf16*)alloc(BTC * 2);
    bf16* xw = (bf16*)alloc(BTC * 2);
    bf16* xk = (bf16*)alloc(BTC * 2);
    bf16* xv = (bf16*)alloc(BTC * 2);
    bf16* xa = (bf16*)alloc(BTC * 2);
    bf16* xg = (bf16*)alloc(BTC * 2);

    bf16* WrT = (bf16*)alloc(1024 * 1024 * 2);
    bf16* WkT = (bf16*)alloc(1024 * 1024 * 2);
    bf16* WvT = (bf16*)alloc(1024 * 1024 * 2);
    bf16* WoT = (bf16*)alloc(1024 * 1024 * 2);
    bf16* w1T = (bf16*)alloc(128 * 1024 * 2);   // 64 rows used, rest benign poison
    bf16* w2T = (bf16*)alloc(1024 * 64 * 2);
    bf16* a1T = (bf16*)alloc(128 * 1024 * 2);
    bf16* a2T = (bf16*)alloc(1024 * 64 * 2);
    bf16* v1T = (bf16*)alloc(128 * 1024 * 2);   // 32 rows used
    bf16* v2T = (bf16*)alloc(1024 * 32 * 2);
    bf16* g1T = (bf16*)alloc(128 * 1024 * 2);
    bf16* g2T = (bf16*)alloc(1024 * 128 * 2);

    bf16* h_w = (bf16*)alloc((size_t)M * 64 * 2);
    bf16* h_a = (bf16*)alloc((size_t)M * 64 * 2);
    bf16* h_v = (bf16*)alloc((size_t)M * 32 * 2);
    bf16* h_g = (bf16*)alloc((size_t)M * 128 * 2);

    float* rbuf  = (float*)alloc(BTC * 4);
    float* kbuf  = (float*)alloc(BTC * 4);
    float* vraw  = (float*)alloc(BTC * 4);   // reused as ybuf after stage-2 v
    float* vbuf  = (float*)alloc(BTC * 4);
    float* dbuf  = (float*)alloc(BTC * 4);   // reused as zbuf (bf16) after scan
    float* abuf  = (float*)alloc(BTC * 4);
    float* kkbuf = (float*)alloc(BTC * 4);   // reused as gbuf after scan

    float* ybuf = vraw;        // alias: vraw dead after stage-2 v GEMM
    bf16*  zbuf = (bf16*)dbuf; // alias: dbuf dead after scan
    float* gbuf = kkbuf;       // alias: kkbuf dead after scan

    (void)in_sizes; (void)n_in; (void)out_size; (void)ws_size;

    // weight transposes+convert [k][n] f32 -> [n][k] bf16
    auto tr = [&](const float* in, bf16* out, int R, int S) {
        dim3 g((S + 31) / 32, (R + 31) / 32);
        transpose_kernel<<<g, 256, 0, stream>>>(in, out, R, S);
    };
    tr(W_r, WrT, 1024, 1024); tr(W_k, WkT, 1024, 1024);
    tr(W_v, WvT, 1024, 1024); tr(W_o, WoT, 1024, 1024);
    tr(w1, w1T, 1024, 64);  tr(w2, w2T, 64, 1024);
    tr(a1, a1T, 1024, 64);  tr(a2, a2T, 64, 1024);
    tr(v1, v1T, 1024, 32);  tr(v2, v2T, 32, 1024);
    tr(g1, g1T, 1024, 128); tr(g2, g2T, 128, 1024);

    // token-shift mix (+ v_first passthrough to second output, f32)
    float* vout = (float*)d_out + BTC;
    mix_kernel<<<BB * TT, 256, 0, stream>>>(x, v_first, x_r, x_w, x_k, x_v, x_a, x_g,
                                            xr, xw, xk, xv, xa, xg, vout);

    auto gg = [&](int Mm, int Nn) { return dim3(Mm / 128, (Nn + 127) / 128); };
    const float* nF = nullptr;

    // big projections
    gemm_kernel<0><<<gg(M, 1024), 256, 0, stream>>>(xr, WrT, M, 1024, 1024, rbuf, nullptr, nF, nF, nF);
    gemm_kernel<0><<<gg(M, 1024), 256, 0, stream>>>(xk, WkT, M, 1024, 1024, kbuf, nullptr, nF, nF, nF);
    gemm_kernel<0><<<gg(M, 1024), 256, 0, stream>>>(xv, WvT, M, 1024, 1024, vraw, nullptr, nF, nF, nF);

    // lora stage 1
    gemm_kernel<2><<<gg(M, 64), 256, 0, stream>>>(xw, w1T, M, 64, 1024, nullptr, h_w, nF, nF, nF);
    gemm_kernel<1><<<gg(M, 64), 256, 0, stream>>>(xa, a1T, M, 64, 1024, nullptr, h_a, nF, nF, nF);
    gemm_kernel<1><<<gg(M, 32), 256, 0, stream>>>(xv, v1T, M, 32, 1024, nullptr, h_v, nF, nF, nF);
    gemm_kernel<3><<<gg(M, 128), 256, 0, stream>>>(xg, g1T, M, 128, 1024, nullptr, h_g, nF, nF, nF);

    // lora stage 2 (fused epilogues)
    gemm_kernel<4><<<gg(M, 1024), 256, 0, stream>>>(h_w, w2T, M, 1024, 64, dbuf, nullptr, w0, nF, nF);
    gemm_kernel<5><<<gg(M, 1024), 256, 0, stream>>>(h_a, a2T, M, 1024, 64, abuf, nullptr, a0, nF, nF);
    gemm_kernel<6><<<gg(M, 1024), 256, 0, stream>>>(h_v, v2T, M, 1024, 32, vbuf, nullptr, v0, vraw, v_first);

    // kk normalize + k scale
    kk_kernel<<<BB * TT * HH / 4, 256, 0, stream>>>(kbuf, abuf, k_k, k_a, kkbuf);

    // sequential recurrence: 128 single-wave blocks (writes ybuf = vraw region)
    scan_kernel<<<BB * HH * 4, 64, 0, stream>>>(rbuf, dbuf, kbuf, vbuf, kkbuf, abuf, ybuf);

    // lora stage 2 g (after scan: gbuf aliases kkbuf)
    gemm_kernel<0><<<gg(M, 1024), 256, 0, stream>>>(h_g, g2T, M, 1024, 128, gbuf, nullptr, nF, nF, nF);

    // groupnorm + residual + gate (writes zbuf = dbuf region)
    gn_kernel<<<BB * TT * HH, 64, 0, stream>>>(ybuf, rbuf, kbuf, vbuf, gbuf, ln_w, ln_b, r_k, zbuf);

    // output projection -> d_out (f32)
    gemm_kernel<0><<<gg(M, 1024), 256, 0, stream>>>(zbuf, WoT, M, 1024, 1024, (float*)d_out, nullptr, nF, nF, nF);
}

// Round 5
// 863.466 us; speedup vs baseline: 1.3662x; 1.2575x over previous
//
#include <hip/hip_runtime.h>
#include <hip/hip_bf16.h>
#include <cstdint>
#include <cstddef>

typedef __hip_bfloat16 bf16;
typedef __bf16 bf16x8 __attribute__((ext_vector_type(8)));
typedef float f32x4 __attribute__((ext_vector_type(4)));

#define BB 2
#define TT 1024
#define CC 1024
#define HH 16

__device__ __forceinline__ bf16 f2b(float v){ return __float2bfloat16(v); }

// ---------------- transpose+convert: f32 [R][S] -> bf16 [S][R] ----------------
__global__ __launch_bounds__(256) void transpose_kernel(const float* __restrict__ in,
                                                        bf16* __restrict__ out, int R, int S)
{
    __shared__ float tile[32][33];
    int s0 = blockIdx.x * 32, r0 = blockIdx.y * 32;
    int tx = threadIdx.x & 31, ty = threadIdx.x >> 5;
#pragma unroll
    for (int i = 0; i < 4; i++) {
        int r = r0 + ty + i * 8, s = s0 + tx;
        if (r < R && s < S) tile[ty + i * 8][tx] = in[(size_t)r * S + s];
    }
    __syncthreads();
#pragma unroll
    for (int i = 0; i < 4; i++) {
        int s = s0 + ty + i * 8, r = r0 + tx;
        if (s < S && r < R) out[(size_t)s * R + r] = f2b(tile[tx][ty + i * 8]);
    }
}

// ---------------- token-shift mix (f32 in -> bf16 out) + v_first passthrough ----------------
__global__ __launch_bounds__(256) void mix_kernel(
    const float* __restrict__ x, const float* __restrict__ vfirst,
    const float* __restrict__ mr, const float* __restrict__ mw, const float* __restrict__ mk,
    const float* __restrict__ mv, const float* __restrict__ ma, const float* __restrict__ mg,
    bf16* __restrict__ xr, bf16* __restrict__ xw, bf16* __restrict__ xk,
    bf16* __restrict__ xv, bf16* __restrict__ xa, bf16* __restrict__ xg,
    float* __restrict__ vout)
{
    int row = blockIdx.x;
    int t = row & (TT - 1);
    size_t base = (size_t)row * CC;
    for (int c = threadIdx.x; c < CC; c += 256) {
        float xc = x[base + c];
        float xp = (t > 0) ? x[base - CC + c] : 0.f;
        float d = xp - xc;
        xr[base + c] = f2b(xc + d * mr[c]);
        xw[base + c] = f2b(xc + d * mw[c]);
        xk[base + c] = f2b(xc + d * mk[c]);
        xv[base + c] = f2b(xc + d * mv[c]);
        xa[base + c] = f2b(xc + d * ma[c]);
        xg[base + c] = f2b(xc + d * mg[c]);
        vout[base + c] = vfirst[base + c];   // exact f32 passthrough
    }
}

// ---------------- MFMA GEMM: out = epilogue(A[M,K] @ BT[N,K]^T), bf16 operands ----------------
// MODE: 0 f32 plain | 1 bf16 plain | 2 bf16 tanh | 3 bf16 sigmoid
//       4 f32 decay(bias) | 5 f32 sigmoid(+bias) | 6 f32 v-mix(bias, aux0=vraw, aux1=vfirst f32)
template<int MODE>
__global__ __launch_bounds__(256) void gemm_kernel(
    const bf16* __restrict__ A, const bf16* __restrict__ BT,
    int M, int N, int K,
    float* __restrict__ outF, bf16* __restrict__ outB,
    const float* __restrict__ bias, const float* __restrict__ aux0,
    const float* __restrict__ aux1)
{
    __shared__ __align__(16) bf16 Atile[128 * 32];
    __shared__ __align__(16) bf16 Btile[128 * 32];
    int tid = threadIdx.x;
    int w = tid >> 6, lane = tid & 63;
    int wr = w >> 1, wc = w & 1;
    int quad = lane >> 4, l16 = lane & 15;
    int m0 = blockIdx.x * 128, n0 = blockIdx.y * 128;

    f32x4 zero = {0.f, 0.f, 0.f, 0.f};
    f32x4 acc[4][4];
#pragma unroll
    for (int i = 0; i < 4; i++)
#pragma unroll
        for (int j = 0; j < 4; j++) acc[i][j] = zero;

    int rr = lane >> 2;            // 0..15
    int cs = lane & 3;             // chunk slot in LDS
    int ra0 = w * 32 + rr;         // rows this lane stages
    int ra1 = ra0 + 16;
    int cg0 = cs ^ ((ra0 >> 1) & 3);   // global chunk (XOR swizzle)
    int cg1 = cs ^ ((ra1 >> 1) & 3);

    for (int k0 = 0; k0 < K; k0 += 32) {
        uint4 av0 = *reinterpret_cast<const uint4*>(A  + (size_t)(m0 + ra0) * K + k0 + cg0 * 8);
        uint4 av1 = *reinterpret_cast<const uint4*>(A  + (size_t)(m0 + ra1) * K + k0 + cg1 * 8);
        uint4 bv0 = *reinterpret_cast<const uint4*>(BT + (size_t)(n0 + ra0) * K + k0 + cg0 * 8);
        uint4 bv1 = *reinterpret_cast<const uint4*>(BT + (size_t)(n0 + ra1) * K + k0 + cg1 * 8);
        __syncthreads();           // previous tile's reads complete
        *reinterpret_cast<uint4*>(&Atile[ra0 * 32 + cs * 8]) = av0;
        *reinterpret_cast<uint4*>(&Atile[ra1 * 32 + cs * 8]) = av1;
        *reinterpret_cast<uint4*>(&Btile[ra0 * 32 + cs * 8]) = bv0;
        *reinterpret_cast<uint4*>(&Btile[ra1 * 32 + cs * 8]) = bv1;
        __syncthreads();           // staging visible

        bf16x8 af[4], bfr[4];
#pragma unroll
        for (int mi = 0; mi < 4; mi++) {
            int m = wr * 64 + mi * 16 + l16;
            int c2 = quad ^ ((m >> 1) & 3);
            af[mi] = *reinterpret_cast<const bf16x8*>(&Atile[m * 32 + c2 * 8]);
        }
#pragma unroll
        for (int ni = 0; ni < 4; ni++) {
            int n = wc * 64 + ni * 16 + l16;
            int c2 = quad ^ ((n >> 1) & 3);
            bfr[ni] = *reinterpret_cast<const bf16x8*>(&Btile[n * 32 + c2 * 8]);
        }
#pragma unroll
        for (int mi = 0; mi < 4; mi++)
#pragma unroll
            for (int ni = 0; ni < 4; ni++)
                acc[mi][ni] = __builtin_amdgcn_mfma_f32_16x16x32_bf16(af[mi], bfr[ni], acc[mi][ni], 0, 0, 0);
    }

#pragma unroll
    for (int mi = 0; mi < 4; mi++)
#pragma unroll
        for (int ni = 0; ni < 4; ni++)
#pragma unroll
            for (int rg = 0; rg < 4; rg++) {
                int m = m0 + wr * 64 + mi * 16 + quad * 4 + rg;
                int n = n0 + wc * 64 + ni * 16 + l16;
                if (n < N) {
                    size_t idx = (size_t)m * N + n;
                    float v = acc[mi][ni][rg];
                    if (MODE == 0) outF[idx] = v;
                    else if (MODE == 1) outB[idx] = f2b(v);
                    else if (MODE == 2) outB[idx] = f2b(tanhf(v));
                    else if (MODE == 3) outB[idx] = f2b(1.f / (1.f + expf(-v)));
                    else if (MODE == 4) {
                        float xx = v + bias[n];
                        float ww = -log1pf(expf(-xx)) - 0.5f;   // -softplus(-x) - 0.5
                        outF[idx] = expf(-expf(ww));            // decay in (0,1)
                    } else if (MODE == 5) {
                        float xx = v + bias[n];
                        outF[idx] = 1.f / (1.f + expf(-xx));
                    } else if (MODE == 6) {
                        float gate = 1.f / (1.f + expf(-(v + bias[n])));
                        float vr = aux0[idx];
                        float vf = aux1[idx];
                        outF[idx] = vr + (vf - vr) * gate;
                    }
                }
            }
}

// ---------------- pack: kk normalize, k scale, bb=kk*a, v -> float4 stream ----------------
// P4[((b*HH+h)*TT + t)*64 + e] = {k_scaled, kk, bb, v}; also writes k_scaled back to kbuf.
__global__ __launch_bounds__(256) void pack_kernel(
    float* __restrict__ k, const float* __restrict__ a, const float* __restrict__ v,
    const float* __restrict__ kkw, const float* __restrict__ kaw,
    float4* __restrict__ P)
{
    int tid = threadIdx.x;
    int wave = tid >> 6, lane = tid & 63;
    int idx = blockIdx.x * 4 + wave;        // (b*TT+t)*HH + h
    size_t off = (size_t)idx * 64 + lane;
    int c = (idx & 15) * 64 + lane;
    float kraw = k[off];
    float av = a[off];
    float kkv = kraw * kkw[c];
    float s = kkv * kkv;
#pragma unroll
    for (int m = 32; m; m >>= 1) s += __shfl_xor(s, m);
    float kkn = kkv / fmaxf(sqrtf(s), 1e-12f);
    float ks = kraw * (1.f + (av - 1.f) * kaw[c]);
    k[off] = ks;                            // write-back for gn_kernel
    int b = idx >> 14;                      // / (TT*HH)
    int h = idx & 15;
    int t = (idx >> 4) & (TT - 1);
    P[(((size_t)(b * HH + h) * TT + t) * 64) + lane] = make_float4(ks, kkn, kkn * av, v[off]);
}

// ---------------- sequential state recurrence (barrier-free, 1 wave/block) ----------------
// Block = 1 wave; owns rows [wq*16, wq*16+16) of one (b,h) state.
// Lane (i = lane>>2, q = lane&3) owns S[row][16q..16q+16).
// Per step: 3 global loads (float4 pack + r + d), 6 ds_write_b32, 21 ds_read (20 b128 + 1 b32).
__global__ __launch_bounds__(64) void scan_kernel(
    const float4* __restrict__ P, const float* __restrict__ rbuf,
    const float* __restrict__ dbuf, float* __restrict__ ybuf)
{
    __shared__ __align__(16) float lds[2][384];
    int lane = threadIdx.x;
    int bh = blockIdx.x >> 2;
    int b = bh >> 4, h = bh & 15;
    int wq = blockIdx.x & 3;
    int row = wq * 16 + (lane >> 2);
    int q = lane & 3, jb = q * 16;

    float S[16];
#pragma unroll
    for (int m = 0; m < 16; m++) S[m] = 0.f;

    const float4* pp = P + (size_t)bh * TT * 64 + lane;
    size_t ebase = (size_t)b * TT * CC + h * 64 + lane;
    const float* pr = rbuf + ebase;
    const float* pd = dbuf + ebase;

    // depth-2 prefetch registers
    float4 F0 = pp[0], F1 = pp[64];
    float R0 = pr[0], R1 = pr[CC];
    float D0 = pd[0], D1 = pd[CC];

    float* py = ybuf + (size_t)b * TT * CC + h * 64 + row;

    for (int t = 0; t < TT; t += 2) {
#pragma unroll
        for (int half = 0; half < 2; half++) {
            float* L = lds[half];
            float4 F = half ? F1 : F0;
            float R = half ? R1 : R0;
            float D = half ? D1 : D0;
            L[lane]       = R;     // r
            L[64 + lane]  = D;     // decay
            L[128 + lane] = F.x;   // k (scaled)
            L[192 + lane] = F.y;   // kk
            L[256 + lane] = F.z;   // bb = kk*a
            L[320 + lane] = F.w;   // v
            {
                int tn = t + 2 + half;
                int tc = (tn < TT) ? tn : TT - 1;
                if (half) { F1 = pp[(size_t)tc * 64]; R1 = pr[(size_t)tc * CC]; D1 = pd[(size_t)tc * CC]; }
                else      { F0 = pp[(size_t)tc * 64]; R0 = pr[(size_t)tc * CC]; D0 = pd[(size_t)tc * CC]; }
            }
            // vector fragment reads (b128, broadcast across 16 lanes, 2-way bank alias = free)
            f32x4 r4[4], d4[4], k4[4], q4[4], b4[4];
#pragma unroll
            for (int m = 0; m < 4; m++) {
                r4[m] = *reinterpret_cast<const f32x4*>(&L[jb + 4 * m]);
                d4[m] = *reinterpret_cast<const f32x4*>(&L[64 + jb + 4 * m]);
                k4[m] = *reinterpret_cast<const f32x4*>(&L[128 + jb + 4 * m]);
                q4[m] = *reinterpret_cast<const f32x4*>(&L[192 + jb + 4 * m]);
                b4[m] = *reinterpret_cast<const f32x4*>(&L[256 + jb + 4 * m]);
            }
            float vi = L[320 + row];

            float sa = 0.f;                   // sa_row = -sum_j S[row][j]*kk_j
#pragma unroll
            for (int m = 0; m < 16; m++) sa -= S[m] * q4[m >> 2][m & 3];
            sa += __shfl_xor(sa, 1); sa += __shfl_xor(sa, 2);

            float o = 0.f;
#pragma unroll
            for (int m = 0; m < 16; m++) {
                int mm = m >> 2, e = m & 3;
                S[m] = S[m] * d4[mm][e] + sa * b4[mm][e] + vi * k4[mm][e];
                o += S[m] * r4[mm][e];
            }
            o += __shfl_xor(o, 1); o += __shfl_xor(o, 2);
            if (q == 0) *py = o;
            py += CC;
        }
    }
}

// ---------------- groupnorm + residual + gate -> z (bf16) ----------------
__global__ __launch_bounds__(64) void gn_kernel(
    const float* __restrict__ y, const float* __restrict__ r, const float* __restrict__ k,
    const float* __restrict__ v, const float* __restrict__ g,
    const float* __restrict__ lnw, const float* __restrict__ lnb,
    const float* __restrict__ rk, bf16* __restrict__ z)
{
    int idx = blockIdx.x;                 // (b*T+t)*16 + h
    int lane = threadIdx.x;
    size_t off = (size_t)idx * 64 + lane;
    int c = (idx & 15) * 64 + lane;
    float yv = y[off];
    float rv = r[off], kv = k[off], vv = v[off];
    float s1 = yv, s2 = yv * yv, s3 = rv * kv * rk[c];
#pragma unroll
    for (int m = 32; m; m >>= 1) {
        s1 += __shfl_xor(s1, m);
        s2 += __shfl_xor(s2, m);
        s3 += __shfl_xor(s3, m);
    }
    float mu = s1 * (1.f / 64.f);
    float var = fmaxf(s2 * (1.f / 64.f) - mu * mu, 0.f);   // guard vs cancellation
    float yn = (yv - mu) * rsqrtf(var + 64e-5f) * lnw[c] + lnb[c];
    float out = (yn + s3 * vv) * g[off];
    z[off] = f2b(out);
}

// ---------------- host ----------------
extern "C" void kernel_launch(void* const* d_in, const int* in_sizes, int n_in,
                              void* d_out, int out_size, void* d_ws, size_t ws_size,
                              hipStream_t stream)
{
    const float* x       = (const float*)d_in[0];
    const float* v_first = (const float*)d_in[1];
    const float* x_r = (const float*)d_in[2];
    const float* x_w = (const float*)d_in[3];
    const float* x_k = (const float*)d_in[4];
    const float* x_v = (const float*)d_in[5];
    const float* x_a = (const float*)d_in[6];
    const float* x_g = (const float*)d_in[7];
    const float* w1 = (const float*)d_in[8];
    const float* w2 = (const float*)d_in[9];
    const float* w0 = (const float*)d_in[10];
    const float* a1 = (const float*)d_in[11];
    const float* a2 = (const float*)d_in[12];
    const float* a0 = (const float*)d_in[13];
    const float* v1 = (const float*)d_in[14];
    const float* v2 = (const float*)d_in[15];
    const float* v0 = (const float*)d_in[16];
    const float* g1 = (const float*)d_in[17];
    const float* g2 = (const float*)d_in[18];
    const float* k_k = (const float*)d_in[19];
    const float* k_a = (const float*)d_in[20];
    const float* r_k = (const float*)d_in[21];
    const float* W_r = (const float*)d_in[22];
    const float* W_k = (const float*)d_in[23];
    const float* W_v = (const float*)d_in[24];
    const float* W_o = (const float*)d_in[25];
    const float* ln_w = (const float*)d_in[26];
    const float* ln_b = (const float*)d_in[27];

    const size_t BTC = (size_t)BB * TT * CC;   // 2M
    const int M = BB * TT;                     // 2048

    char* ws = (char*)d_ws;
    size_t off = 0;
    auto alloc = [&](size_t bytes) -> char* {
        char* p = ws + off;
        off += (bytes + 255) & ~(size_t)255;
        return p;
    };

    // ---- region0: dead before pack_kernel runs; P4 aliases this space ----
    bf16* xr = (bf16*)alloc(BTC * 2);
    bf16* xw = (bf16*)alloc(BTC * 2);
    bf16* xk = (bf16*)alloc(BTC * 2);
    bf16* xv = (bf16*)alloc(BTC * 2);
    bf16* xa = (bf16*)alloc(BTC * 2);
    bf16* xg = (bf16*)alloc(BTC * 2);
    bf16* WrT = (bf16*)alloc(1024 * 1024 * 2);
    bf16* WkT = (bf16*)alloc(1024 * 1024 * 2);
    bf16* WvT = (bf16*)alloc(1024 * 1024 * 2);
    bf16* w1T = (bf16*)alloc(128 * 1024 * 2);   // 64 rows used, rest benign poison
    bf16* w2T = (bf16*)alloc(1024 * 64 * 2);
    bf16* a1T = (bf16*)alloc(128 * 1024 * 2);
    bf16* a2T = (bf16*)alloc(1024 * 64 * 2);
    bf16* v1T = (bf16*)alloc(128 * 1024 * 2);   // 32 rows used
    bf16* v2T = (bf16*)alloc(1024 * 32 * 2);
    bf16* g1T = (bf16*)alloc(128 * 1024 * 2);
    bf16* h_w = (bf16*)alloc((size_t)M * 64 * 2);
    bf16* h_a = (bf16*)alloc((size_t)M * 64 * 2);
    bf16* h_v = (bf16*)alloc((size_t)M * 32 * 2);

    // P4 aliases region0 (32 MB); continue allocations past max(region0, P4)
    float4* P4 = (float4*)ws;
    size_t p4_end = BTC * 16;                  // 33,554,432
    if (off < p4_end) off = p4_end;
    off = (off + 255) & ~(size_t)255;

    // ---- live across pack/scan ----
    bf16* g2T = (bf16*)alloc(1024 * 128 * 2);  // used after scan
    bf16* h_g = (bf16*)alloc((size_t)M * 128 * 2);
    bf16* WoT = (bf16*)alloc(1024 * 1024 * 2);

    float* rbuf  = (float*)alloc(BTC * 4);
    float* kbuf  = (float*)alloc(BTC * 4);
    float* vraw  = (float*)alloc(BTC * 4);   // reused as ybuf after stage-2 v
    float* vbuf  = (float*)alloc(BTC * 4);
    float* dbuf  = (float*)alloc(BTC * 4);   // reused as zbuf (bf16) after scan
    float* abuf  = (float*)alloc(BTC * 4);

    float* ybuf = vraw;        // alias: vraw dead after stage-2 v GEMM
    bf16*  zbuf = (bf16*)dbuf; // alias: dbuf dead after scan (gn writes after scan)
    float* gbuf = (float*)P4;  // alias: P4 dead after scan (g2 GEMM runs after scan)

    (void)in_sizes; (void)n_in; (void)out_size; (void)ws_size;

    // weight transposes+convert [k][n] f32 -> [n][k] bf16
    auto tr = [&](const float* in, bf16* out, int R, int S) {
        dim3 g((S + 31) / 32, (R + 31) / 32);
        transpose_kernel<<<g, 256, 0, stream>>>(in, out, R, S);
    };
    tr(W_r, WrT, 1024, 1024); tr(W_k, WkT, 1024, 1024);
    tr(W_v, WvT, 1024, 1024); tr(W_o, WoT, 1024, 1024);
    tr(w1, w1T, 1024, 64);  tr(w2, w2T, 64, 1024);
    tr(a1, a1T, 1024, 64);  tr(a2, a2T, 64, 1024);
    tr(v1, v1T, 1024, 32);  tr(v2, v2T, 32, 1024);
    tr(g1, g1T, 1024, 128); tr(g2, g2T, 128, 1024);

    // token-shift mix (+ v_first passthrough to second output, f32)
    float* vout = (float*)d_out + BTC;
    mix_kernel<<<BB * TT, 256, 0, stream>>>(x, v_first, x_r, x_w, x_k, x_v, x_a, x_g,
                                            xr, xw, xk, xv, xa, xg, vout);

    auto gg = [&](int Mm, int Nn) { return dim3(Mm / 128, (Nn + 127) / 128); };
    const float* nF = nullptr;

    // big projections
    gemm_kernel<0><<<gg(M, 1024), 256, 0, stream>>>(xr, WrT, M, 1024, 1024, rbuf, nullptr, nF, nF, nF);
    gemm_kernel<0><<<gg(M, 1024), 256, 0, stream>>>(xk, WkT, M, 1024, 1024, kbuf, nullptr, nF, nF, nF);
    gemm_kernel<0><<<gg(M, 1024), 256, 0, stream>>>(xv, WvT, M, 1024, 1024, vraw, nullptr, nF, nF, nF);

    // lora stage 1
    gemm_kernel<2><<<gg(M, 64), 256, 0, stream>>>(xw, w1T, M, 64, 1024, nullptr, h_w, nF, nF, nF);
    gemm_kernel<1><<<gg(M, 64), 256, 0, stream>>>(xa, a1T, M, 64, 1024, nullptr, h_a, nF, nF, nF);
    gemm_kernel<1><<<gg(M, 32), 256, 0, stream>>>(xv, v1T, M, 32, 1024, nullptr, h_v, nF, nF, nF);
    gemm_kernel<3><<<gg(M, 128), 256, 0, stream>>>(xg, g1T, M, 128, 1024, nullptr, h_g, nF, nF, nF);

    // lora stage 2 (fused epilogues)
    gemm_kernel<4><<<gg(M, 1024), 256, 0, stream>>>(h_w, w2T, M, 1024, 64, dbuf, nullptr, w0, nF, nF);
    gemm_kernel<5><<<gg(M, 1024), 256, 0, stream>>>(h_a, a2T, M, 1024, 64, abuf, nullptr, a0, nF, nF);
    gemm_kernel<6><<<gg(M, 1024), 256, 0, stream>>>(h_v, v2T, M, 1024, 32, vbuf, nullptr, v0, vraw, v_first);

    // pack: kk normalize + k scale + bb + v -> P4 (also writes scaled k back to kbuf)
    pack_kernel<<<BB * TT * HH / 4, 256, 0, stream>>>(kbuf, abuf, vbuf, k_k, k_a, P4);

    // sequential recurrence: 128 single-wave blocks (writes ybuf = vraw region)
    scan_kernel<<<BB * HH * 4, 64, 0, stream>>>(P4, rbuf, dbuf, ybuf);

    // lora stage 2 g (after scan: gbuf aliases P4)
    gemm_kernel<0><<<gg(M, 1024), 256, 0, stream>>>(h_g, g2T, M, 1024, 128, gbuf, nullptr, nF, nF, nF);

    // groupnorm + residual + gate (writes zbuf = dbuf region)
    gn_kernel<<<BB * TT * HH, 64, 0, stream>>>(ybuf, rbuf, kbuf, vbuf, gbuf, ln_w, ln_b, r_k, zbuf);

    // output projection -> d_out (f32)
    gemm_kernel<0><<<gg(M, 1024), 256, 0, stream>>>(zbuf, WoT, M, 1024, 1024, (float*)d_out, nullptr, nF, nF, nF);
}

// Round 6
// 641.456 us; speedup vs baseline: 1.8391x; 1.3461x over previous
//
#include <hip/hip_runtime.h>
#include <hip/hip_bf16.h>
#include <cstdint>
#include <cstddef>

typedef __hip_bfloat16 bf16;
typedef __bf16 bf16x8 __attribute__((ext_vector_type(8)));
typedef float f32x4 __attribute__((ext_vector_type(4)));

#define BB 2
#define TT 1024
#define CC 1024
#define HH 16

__device__ __forceinline__ bf16 f2b(float v){ return __float2bfloat16(v); }

// quad (4-lane) sum via DPP quad_perm — VALU latency, no DS pipe
__device__ __forceinline__ float quad_add(float x) {
    x += __int_as_float(__builtin_amdgcn_mov_dpp(__float_as_int(x), 0xB1, 0xF, 0xF, true)); // xor 1
    x += __int_as_float(__builtin_amdgcn_mov_dpp(__float_as_int(x), 0x4E, 0xF, 0xF, true)); // xor 2
    return x;
}

// ---------------- batched transpose+convert: f32 [R][S] -> bf16 [S][R] ----------------
struct TrDesc { const float* in; bf16* out; int R, S; };
struct TrArgs { TrDesc d[12]; };

__global__ __launch_bounds__(256) void transpose_batch(TrArgs args)
{
    TrDesc t = args.d[blockIdx.z];
    __shared__ float tile[32][33];
    int s0 = blockIdx.x * 32, r0 = blockIdx.y * 32;
    if (s0 >= t.S || r0 >= t.R) return;      // block-uniform early exit
    int tx = threadIdx.x & 31, ty = threadIdx.x >> 5;
#pragma unroll
    for (int i = 0; i < 4; i++) {
        int r = r0 + ty + i * 8, s = s0 + tx;
        if (r < t.R && s < t.S) tile[ty + i * 8][tx] = t.in[(size_t)r * t.S + s];
    }
    __syncthreads();
#pragma unroll
    for (int i = 0; i < 4; i++) {
        int s = s0 + ty + i * 8, r = r0 + tx;
        if (s < t.S && r < t.R) t.out[(size_t)s * t.R + r] = f2b(tile[tx][ty + i * 8]);
    }
}

// ---------------- token-shift mix (f32 in -> bf16 out) + v_first passthrough ----------------
__global__ __launch_bounds__(256) void mix_kernel(
    const float* __restrict__ x, const float* __restrict__ vfirst,
    const float* __restrict__ mr, const float* __restrict__ mw, const float* __restrict__ mk,
    const float* __restrict__ mv, const float* __restrict__ ma, const float* __restrict__ mg,
    bf16* __restrict__ xr, bf16* __restrict__ xw, bf16* __restrict__ xk,
    bf16* __restrict__ xv, bf16* __restrict__ xa, bf16* __restrict__ xg,
    float* __restrict__ vout)
{
    int row = blockIdx.x;
    int t = row & (TT - 1);
    size_t base = (size_t)row * CC;
    for (int c = threadIdx.x; c < CC; c += 256) {
        float xc = x[base + c];
        float xp = (t > 0) ? x[base - CC + c] : 0.f;
        float d = xp - xc;
        xr[base + c] = f2b(xc + d * mr[c]);
        xw[base + c] = f2b(xc + d * mw[c]);
        xk[base + c] = f2b(xc + d * mk[c]);
        xv[base + c] = f2b(xc + d * mv[c]);
        xa[base + c] = f2b(xc + d * ma[c]);
        xg[base + c] = f2b(xc + d * mg[c]);
        vout[base + c] = vfirst[base + c];   // exact f32 passthrough
    }
}

// ---------------- shared MFMA tile body: 128x128 tile of A[M,K] @ BT[N,K]^T ----------------
template <class EmitF>
__device__ __forceinline__ void gemm_tile(const bf16* __restrict__ A, const bf16* __restrict__ BT,
                                          int K, int m0, int n0, EmitF emit)
{
    __shared__ __align__(16) bf16 Atile[128 * 32];
    __shared__ __align__(16) bf16 Btile[128 * 32];
    int tid = threadIdx.x;
    int w = tid >> 6, lane = tid & 63;
    int wr = w >> 1, wc = w & 1;
    int quad = lane >> 4, l16 = lane & 15;

    f32x4 zero = {0.f, 0.f, 0.f, 0.f};
    f32x4 acc[4][4];
#pragma unroll
    for (int i = 0; i < 4; i++)
#pragma unroll
        for (int j = 0; j < 4; j++) acc[i][j] = zero;

    int rr = lane >> 2;            // 0..15
    int cs = lane & 3;             // chunk slot in LDS
    int ra0 = w * 32 + rr;         // rows this lane stages
    int ra1 = ra0 + 16;
    int cg0 = cs ^ ((ra0 >> 1) & 3);   // global chunk (XOR swizzle)
    int cg1 = cs ^ ((ra1 >> 1) & 3);

    for (int k0 = 0; k0 < K; k0 += 32) {
        uint4 av0 = *reinterpret_cast<const uint4*>(A  + (size_t)(m0 + ra0) * K + k0 + cg0 * 8);
        uint4 av1 = *reinterpret_cast<const uint4*>(A  + (size_t)(m0 + ra1) * K + k0 + cg1 * 8);
        uint4 bv0 = *reinterpret_cast<const uint4*>(BT + (size_t)(n0 + ra0) * K + k0 + cg0 * 8);
        uint4 bv1 = *reinterpret_cast<const uint4*>(BT + (size_t)(n0 + ra1) * K + k0 + cg1 * 8);
        __syncthreads();           // previous tile's reads complete
        *reinterpret_cast<uint4*>(&Atile[ra0 * 32 + cs * 8]) = av0;
        *reinterpret_cast<uint4*>(&Atile[ra1 * 32 + cs * 8]) = av1;
        *reinterpret_cast<uint4*>(&Btile[ra0 * 32 + cs * 8]) = bv0;
        *reinterpret_cast<uint4*>(&Btile[ra1 * 32 + cs * 8]) = bv1;
        __syncthreads();           // staging visible

        bf16x8 af[4], bfr[4];
#pragma unroll
        for (int mi = 0; mi < 4; mi++) {
            int m = wr * 64 + mi * 16 + l16;
            int c2 = quad ^ ((m >> 1) & 3);
            af[mi] = *reinterpret_cast<const bf16x8*>(&Atile[m * 32 + c2 * 8]);
        }
#pragma unroll
        for (int ni = 0; ni < 4; ni++) {
            int n = wc * 64 + ni * 16 + l16;
            int c2 = quad ^ ((n >> 1) & 3);
            bfr[ni] = *reinterpret_cast<const bf16x8*>(&Btile[n * 32 + c2 * 8]);
        }
#pragma unroll
        for (int mi = 0; mi < 4; mi++)
#pragma unroll
            for (int ni = 0; ni < 4; ni++)
                acc[mi][ni] = __builtin_amdgcn_mfma_f32_16x16x32_bf16(af[mi], bfr[ni], acc[mi][ni], 0, 0, 0);
    }

#pragma unroll
    for (int mi = 0; mi < 4; mi++)
#pragma unroll
        for (int ni = 0; ni < 4; ni++)
#pragma unroll
            for (int rg = 0; rg < 4; rg++) {
                int m = m0 + wr * 64 + mi * 16 + quad * 4 + rg;
                int n = n0 + wc * 64 + ni * 16 + l16;
                emit(m, n, acc[mi][ni][rg]);
            }
}

// ---------------- big projections r/k/v: z-batched, N=K=1024, f32 out ----------------
struct B3Args { const bf16* A[3]; const bf16* BT[3]; float* out[3]; };
__global__ __launch_bounds__(256) void big3_kernel(B3Args args)
{
    int z = blockIdx.z;
    float* out = args.out[z];
    gemm_tile(args.A[z], args.BT[z], 1024, blockIdx.x * 128, blockIdx.y * 128,
              [&](int m, int n, float v) { out[(size_t)m * 1024 + n] = v; });
}

// ---------------- lora stage 1: z-batched (different A per z), small N, bf16 out ----------------
struct L1Desc { const bf16* A; const bf16* BT; bf16* outB; int N; int mode; }; // mode: 0 plain, 2 tanh, 3 sigmoid
struct L1Args { L1Desc d[4]; };
__global__ __launch_bounds__(256) void lora1_kernel(L1Args args)
{
    L1Desc dz = args.d[blockIdx.z];
    gemm_tile(dz.A, dz.BT, 1024, blockIdx.x * 128, 0,
              [&](int m, int n, float v) {
                  if (n < dz.N) {
                      float r = (dz.mode == 2) ? tanhf(v)
                              : (dz.mode == 3) ? 1.f / (1.f + expf(-v)) : v;
                      dz.outB[(size_t)m * dz.N + n] = f2b(r);
                  }
              });
}

// ---------------- lora stage 2 (+g2): z-batched, N=1024, f32 out, fused epilogues ----------------
struct L2Desc { const bf16* A; const bf16* BT; const float* bias; float* outF; int K; int mode; };
struct L2Args { L2Desc d[4]; const float* vraw; const float* vfirst; };
__global__ __launch_bounds__(256) void lora2_kernel(L2Args args)
{
    L2Desc dz = args.d[blockIdx.z];
    gemm_tile(dz.A, dz.BT, dz.K, blockIdx.x * 128, blockIdx.y * 128,
              [&](int m, int n, float v) {
                  size_t idx = (size_t)m * 1024 + n;
                  if (dz.mode == 4) {
                      float xx = v + dz.bias[n];
                      float ww = -log1pf(expf(-xx)) - 0.5f;   // -softplus(-x) - 0.5
                      dz.outF[idx] = expf(-expf(ww));
                  } else if (dz.mode == 5) {
                      float xx = v + dz.bias[n];
                      dz.outF[idx] = 1.f / (1.f + expf(-xx));
                  } else if (dz.mode == 6) {
                      float gate = 1.f / (1.f + expf(-(v + dz.bias[n])));
                      float vr = args.vraw[idx];
                      dz.outF[idx] = vr + (args.vfirst[idx] - vr) * gate;
                  } else {
                      dz.outF[idx] = v;
                  }
              });
}

// ---------------- final output projection ----------------
__global__ __launch_bounds__(256) void final_kernel(const bf16* __restrict__ A, const bf16* __restrict__ BT,
                                                    float* __restrict__ out)
{
    gemm_tile(A, BT, 1024, blockIdx.x * 128, blockIdx.y * 128,
              [&](int m, int n, float v) { out[(size_t)m * 1024 + n] = v; });
}

// ---------------- pack: kk norm, k scale, bb, v -> float4 stream; Bt/Ct -> float2 stream ----------------
// P4[((b*HH+h)*TT+t)*64 + e] = {k_scaled, kk, bb, v}; BC[(b*HH+h)*TT+t] = {Σ bb·r, Σ k·r}
__global__ __launch_bounds__(256) void pack_kernel(
    float* __restrict__ k, const float* __restrict__ a, const float* __restrict__ v,
    const float* __restrict__ r,
    const float* __restrict__ kkw, const float* __restrict__ kaw,
    float4* __restrict__ P, float2* __restrict__ BC)
{
    int tid = threadIdx.x;
    int wave = tid >> 6, lane = tid & 63;
    int idx = blockIdx.x * 4 + wave;        // (b*TT+t)*HH + h
    size_t off = (size_t)idx * 64 + lane;
    int c = (idx & 15) * 64 + lane;
    float kraw = k[off];
    float av = a[off];
    float kkv = kraw * kkw[c];
    float s = kkv * kkv;
#pragma unroll
    for (int m = 32; m; m >>= 1) s += __shfl_xor(s, m);
    float kkn = kkv / fmaxf(sqrtf(s), 1e-12f);
    float ks = kraw * (1.f + (av - 1.f) * kaw[c]);
    k[off] = ks;                            // write-back for gn_kernel
    float bb = kkn * av;
    float rv = r[off];
    float bt = bb * rv, ct = ks * rv;
#pragma unroll
    for (int m = 32; m; m >>= 1) { bt += __shfl_xor(bt, m); ct += __shfl_xor(ct, m); }
    int b = idx >> 14;                      // / (TT*HH)
    int h = idx & 15;
    int t = (idx >> 4) & (TT - 1);
    size_t sidx = (size_t)(b * HH + h) * TT + t;
    P[sidx * 64 + lane] = make_float4(ks, kkn, bb, v[off]);
    if (lane == 0) BC[sidx] = make_float2(bt, ct);
}

// ---------------- sequential state recurrence ----------------
// 1 wave/block; wave owns rows [wq*16, wq*16+16). Lane (i=lane>>2, q=lane&3) owns S[row][16q..16q+16).
// 4-buffer LDS ring staged 2 steps ahead (no write->read wait); DPP quad reductions;
// o = Σ(S_old·d·r) + sa·Bt + vi·Ct with Bt/Ct precomputed (S-update off o's critical path).
__global__ __launch_bounds__(64) void scan_kernel(
    const float4* __restrict__ P, const float* __restrict__ rbuf,
    const float* __restrict__ dbuf, const float2* __restrict__ BC,
    float* __restrict__ ybuf)
{
    __shared__ __align__(16) float L[4][384];
    const int lane = threadIdx.x;
    const int bh = blockIdx.x >> 2;
    const int b = bh >> 4, h = bh & 15;
    const int wq = blockIdx.x & 3;
    const int row = wq * 16 + (lane >> 2);
    const int q = lane & 3, jb = q * 16;

    float S[16];
#pragma unroll
    for (int m = 0; m < 16; m++) S[m] = 0.f;

    const float4* pp = P + (size_t)bh * TT * 64 + lane;
    size_t ebase = (size_t)b * TT * CC + h * 64 + lane;
    const float* pr = rbuf + ebase;
    const float* pd = dbuf + ebase;
    const float2* pbc = BC + (size_t)bh * TT;

    // stage t=0, t=1 directly into L0, L1 (same-wave in-order DS: no barrier needed)
    {
        float4 f0 = pp[0], f1 = pp[64];
        float r0 = pr[0], r1 = pr[CC];
        float d0 = pd[0], d1 = pd[CC];
        L[0][lane] = r0; L[0][64 + lane] = d0; L[0][128 + lane] = f0.x;
        L[0][192 + lane] = f0.y; L[0][256 + lane] = f0.z; L[0][320 + lane] = f0.w;
        L[1][lane] = r1; L[1][64 + lane] = d1; L[1][128 + lane] = f1.x;
        L[1][192 + lane] = f1.y; L[1][256 + lane] = f1.z; L[1][320 + lane] = f1.w;
    }
    float2 bc0 = pbc[0], bc1 = pbc[1], bc2 = make_float2(0, 0), bc3 = make_float2(0, 0);
    float4 Fg[2]; float Rg[2], Dg[2]; float2 Cg[2];
    Fg[0] = pp[2 * 64]; Rg[0] = pr[2 * CC]; Dg[0] = pd[2 * CC]; Cg[0] = pbc[2];
    Fg[1] = pp[3 * 64]; Rg[1] = pr[3 * CC]; Dg[1] = pd[3 * CC]; Cg[1] = pbc[3];

    float* py = ybuf + (size_t)b * TT * CC + h * 64 + row;

    for (int t = 0; t < TT; t += 4) {
#pragma unroll
        for (int u = 0; u < 4; u++) {
            const int g = u & 1;
            const float* Lc = L[u];               // data for step t+u
            float* Ln = L[(u + 2) & 3];           // will hold t+u+2 (last read 2 iters ago)
            float2 bc = (u == 0) ? bc0 : (u == 1) ? bc1 : (u == 2) ? bc2 : bc3;

            // fragment reads (kk first: heads the critical chain)
            f32x4 q4[4], d4[4], k4[4], b4[4], r4[4];
#pragma unroll
            for (int m = 0; m < 4; m++) q4[m] = *(const f32x4*)&Lc[192 + jb + 4 * m];
#pragma unroll
            for (int m = 0; m < 4; m++) d4[m] = *(const f32x4*)&Lc[64 + jb + 4 * m];
#pragma unroll
            for (int m = 0; m < 4; m++) r4[m] = *(const f32x4*)&Lc[jb + 4 * m];
#pragma unroll
            for (int m = 0; m < 4; m++) k4[m] = *(const f32x4*)&Lc[128 + jb + 4 * m];
#pragma unroll
            for (int m = 0; m < 4; m++) b4[m] = *(const f32x4*)&Lc[256 + jb + 4 * m];
            float vi = Lc[320 + row];

            // stage t+u+2 (loaded 2 iters ago) and refill prefetch regs with t+u+4
            Ln[lane] = Rg[g]; Ln[64 + lane] = Dg[g];
            Ln[128 + lane] = Fg[g].x; Ln[192 + lane] = Fg[g].y;
            Ln[256 + lane] = Fg[g].z; Ln[320 + lane] = Fg[g].w;
            if (u == 0) bc2 = Cg[g]; else if (u == 1) bc3 = Cg[g];
            else if (u == 2) bc0 = Cg[g]; else bc1 = Cg[g];
            {
                int tn = t + u + 4; if (tn > TT - 1) tn = TT - 1;
                Fg[g] = pp[(size_t)tn * 64];
                Rg[g] = pr[(size_t)tn * CC];
                Dg[g] = pd[(size_t)tn * CC];
                Cg[g] = pbc[tn];
            }

            // sa and od partials: 4 independent accumulator chains each
            float s0 = 0, s1 = 0, s2 = 0, s3 = 0;
            float o0 = 0, o1 = 0, o2 = 0, o3 = 0;
#pragma unroll
            for (int m = 0; m < 4; m++) {
                s0 = fmaf(S[4 * m + 0], q4[m][0], s0);
                s1 = fmaf(S[4 * m + 1], q4[m][1], s1);
                s2 = fmaf(S[4 * m + 2], q4[m][2], s2);
                s3 = fmaf(S[4 * m + 3], q4[m][3], s3);
                o0 = fmaf(S[4 * m + 0] * d4[m][0], r4[m][0], o0);
                o1 = fmaf(S[4 * m + 1] * d4[m][1], r4[m][1], o1);
                o2 = fmaf(S[4 * m + 2] * d4[m][2], r4[m][2], o2);
                o3 = fmaf(S[4 * m + 3] * d4[m][3], r4[m][3], o3);
            }
            float sa = -((s0 + s1) + (s2 + s3));
            sa = quad_add(sa);                    // full-row sa (all 4 lanes)
            float od = quad_add((o0 + o1) + (o2 + o3));
            float o = fmaf(vi, bc.y, fmaf(sa, bc.x, od));

#pragma unroll
            for (int m = 0; m < 16; m++) {
                int mm = m >> 2, e = m & 3;
                S[m] = fmaf(vi, k4[mm][e], fmaf(sa, b4[mm][e], S[m] * d4[mm][e]));
            }
            if (q == 0) *py = o;
            py += CC;
        }
    }
}

// ---------------- groupnorm + residual + gate -> z (bf16) ----------------
__global__ __launch_bounds__(64) void gn_kernel(
    const float* __restrict__ y, const float* __restrict__ r, const float* __restrict__ k,
    const float* __restrict__ v, const float* __restrict__ g,
    const float* __restrict__ lnw, const float* __restrict__ lnb,
    const float* __restrict__ rk, bf16* __restrict__ z)
{
    int idx = blockIdx.x;                 // (b*T+t)*16 + h
    int lane = threadIdx.x;
    size_t off = (size_t)idx * 64 + lane;
    int c = (idx & 15) * 64 + lane;
    float yv = y[off];
    float rv = r[off], kv = k[off], vv = v[off];
    float s1 = yv, s2 = yv * yv, s3 = rv * kv * rk[c];
#pragma unroll
    for (int m = 32; m; m >>= 1) {
        s1 += __shfl_xor(s1, m);
        s2 += __shfl_xor(s2, m);
        s3 += __shfl_xor(s3, m);
    }
    float mu = s1 * (1.f / 64.f);
    float var = fmaxf(s2 * (1.f / 64.f) - mu * mu, 0.f);
    float yn = (yv - mu) * rsqrtf(var + 64e-5f) * lnw[c] + lnb[c];
    float out = (yn + s3 * vv) * g[off];
    z[off] = f2b(out);
}

// ---------------- host ----------------
extern "C" void kernel_launch(void* const* d_in, const int* in_sizes, int n_in,
                              void* d_out, int out_size, void* d_ws, size_t ws_size,
                              hipStream_t stream)
{
    const float* x       = (const float*)d_in[0];
    const float* v_first = (const float*)d_in[1];
    const float* x_r = (const float*)d_in[2];
    const float* x_w = (const float*)d_in[3];
    const float* x_k = (const float*)d_in[4];
    const float* x_v = (const float*)d_in[5];
    const float* x_a = (const float*)d_in[6];
    const float* x_g = (const float*)d_in[7];
    const float* w1 = (const float*)d_in[8];
    const float* w2 = (const float*)d_in[9];
    const float* w0 = (const float*)d_in[10];
    const float* a1 = (const float*)d_in[11];
    const float* a2 = (const float*)d_in[12];
    const float* a0 = (const float*)d_in[13];
    const float* v1 = (const float*)d_in[14];
    const float* v2 = (const float*)d_in[15];
    const float* v0 = (const float*)d_in[16];
    const float* g1 = (const float*)d_in[17];
    const float* g2 = (const float*)d_in[18];
    const float* k_k = (const float*)d_in[19];
    const float* k_a = (const float*)d_in[20];
    const float* r_k = (const float*)d_in[21];
    const float* W_r = (const float*)d_in[22];
    const float* W_k = (const float*)d_in[23];
    const float* W_v = (const float*)d_in[24];
    const float* W_o = (const float*)d_in[25];
    const float* ln_w = (const float*)d_in[26];
    const float* ln_b = (const float*)d_in[27];

    const size_t BTC = (size_t)BB * TT * CC;   // 2M
    const int M = BB * TT;                     // 2048

    char* ws = (char*)d_ws;
    size_t off = 0;
    auto alloc = [&](size_t bytes) -> char* {
        char* p = ws + off;
        off += (bytes + 255) & ~(size_t)255;
        return p;
    };

    // ---- region0: everything here is dead before pack_kernel; P4 aliases it ----
    bf16* xr = (bf16*)alloc(BTC * 2);
    bf16* xw = (bf16*)alloc(BTC * 2);
    bf16* xk = (bf16*)alloc(BTC * 2);
    bf16* xv = (bf16*)alloc(BTC * 2);
    bf16* xa = (bf16*)alloc(BTC * 2);
    bf16* xg = (bf16*)alloc(BTC * 2);
    bf16* WrT = (bf16*)alloc(1024 * 1024 * 2);
    bf16* WkT = (bf16*)alloc(1024 * 1024 * 2);
    bf16* WvT = (bf16*)alloc(1024 * 1024 * 2);
    bf16* w1T = (bf16*)alloc(128 * 1024 * 2);   // 64 rows used, pad benign
    bf16* a1T = (bf16*)alloc(128 * 1024 * 2);
    bf16* v1T = (bf16*)alloc(128 * 1024 * 2);   // 32 rows used
    bf16* g1T = (bf16*)alloc(128 * 1024 * 2);
    bf16* w2T = (bf16*)alloc(1024 * 64 * 2);
    bf16* a2T = (bf16*)alloc(1024 * 64 * 2);
    bf16* v2T = (bf16*)alloc(1024 * 32 * 2);
    bf16* g2T = (bf16*)alloc(1024 * 128 * 2);
    bf16* h_w = (bf16*)alloc((size_t)M * 64 * 2);
    bf16* h_a = (bf16*)alloc((size_t)M * 64 * 2);
    bf16* h_v = (bf16*)alloc((size_t)M * 32 * 2);
    bf16* h_g = (bf16*)alloc((size_t)M * 128 * 2);

    // P4 aliases region0 (32 MB); continue past max(region0, P4)
    float4* P4 = (float4*)ws;
    size_t p4_end = BTC * 16;
    if (off < p4_end) off = p4_end;
    off = (off + 255) & ~(size_t)255;

    // ---- live across pack/scan ----
    bf16* WoT = (bf16*)alloc(1024 * 1024 * 2);
    float2* BC = (float2*)alloc((size_t)BB * HH * TT * 8);
    float* rbuf = (float*)alloc(BTC * 4);
    float* kbuf = (float*)alloc(BTC * 4);
    float* vraw = (float*)alloc(BTC * 4);   // reused as ybuf after lora2
    float* vbuf = (float*)alloc(BTC * 4);
    float* dbuf = (float*)alloc(BTC * 4);   // reused as zbuf (bf16) after scan
    float* abuf = (float*)alloc(BTC * 4);
    float* gbuf = (float*)alloc(BTC * 4);

    float* ybuf = vraw;
    bf16*  zbuf = (bf16*)dbuf;

    (void)in_sizes; (void)n_in; (void)out_size; (void)ws_size;

    // 1) all weight transposes in one launch
    TrArgs ta;
    ta.d[0]  = {W_r, WrT, 1024, 1024};
    ta.d[1]  = {W_k, WkT, 1024, 1024};
    ta.d[2]  = {W_v, WvT, 1024, 1024};
    ta.d[3]  = {W_o, WoT, 1024, 1024};
    ta.d[4]  = {w1, w1T, 1024, 64};
    ta.d[5]  = {a1, a1T, 1024, 64};
    ta.d[6]  = {v1, v1T, 1024, 32};
    ta.d[7]  = {g1, g1T, 1024, 128};
    ta.d[8]  = {w2, w2T, 64, 1024};
    ta.d[9]  = {a2, a2T, 64, 1024};
    ta.d[10] = {v2, v2T, 32, 1024};
    ta.d[11] = {g2, g2T, 128, 1024};
    transpose_batch<<<dim3(32, 32, 12), 256, 0, stream>>>(ta);

    // 2) token-shift mix (+ v_first passthrough)
    float* vout = (float*)d_out + BTC;
    mix_kernel<<<BB * TT, 256, 0, stream>>>(x, v_first, x_r, x_w, x_k, x_v, x_a, x_g,
                                            xr, xw, xk, xv, xa, xg, vout);

    // 3) big projections r/k/v
    B3Args b3;
    b3.A[0] = xr; b3.A[1] = xk; b3.A[2] = xv;
    b3.BT[0] = WrT; b3.BT[1] = WkT; b3.BT[2] = WvT;
    b3.out[0] = rbuf; b3.out[1] = kbuf; b3.out[2] = vraw;
    big3_kernel<<<dim3(16, 8, 3), 256, 0, stream>>>(b3);

    // 4) lora stage 1
    L1Args l1;
    l1.d[0] = {xw, w1T, h_w, 64, 2};
    l1.d[1] = {xa, a1T, h_a, 64, 0};
    l1.d[2] = {xv, v1T, h_v, 32, 0};
    l1.d[3] = {xg, g1T, h_g, 128, 3};
    lora1_kernel<<<dim3(16, 1, 4), 256, 0, stream>>>(l1);

    // 5) lora stage 2 + g2
    L2Args l2;
    l2.d[0] = {h_w, w2T, w0, dbuf, 64, 4};
    l2.d[1] = {h_a, a2T, a0, abuf, 64, 5};
    l2.d[2] = {h_v, v2T, v0, vbuf, 32, 6};
    l2.d[3] = {h_g, g2T, nullptr, gbuf, 128, 0};
    l2.vraw = vraw; l2.vfirst = v_first;
    lora2_kernel<<<dim3(16, 8, 4), 256, 0, stream>>>(l2);

    // 6) pack (+ Bt/Ct precompute; writes scaled k back to kbuf)
    pack_kernel<<<BB * TT * HH / 4, 256, 0, stream>>>(kbuf, abuf, vbuf, rbuf, k_k, k_a, P4, BC);

    // 7) sequential recurrence (writes ybuf = vraw region)
    scan_kernel<<<BB * HH * 4, 64, 0, stream>>>(P4, rbuf, dbuf, BC, ybuf);

    // 8) groupnorm + residual + gate (writes zbuf = dbuf region)
    gn_kernel<<<BB * TT * HH, 64, 0, stream>>>(ybuf, rbuf, kbuf, vbuf, gbuf, ln_w, ln_b, r_k, zbuf);

    // 9) output projection -> d_out (f32)
    final_kernel<<<dim3(16, 8), 256, 0, stream>>>(zbuf, WoT, (float*)d_out);
}